// Round 2
// baseline (487.857 us; speedup 1.0000x reference)
//
#include <hip/hip_runtime.h>
#include <math.h>

#define N_NODES 50000
#define N_EDGES 800000
#define NFEAT 256
#define NHID 64
#define NCLASS 40

// ---------------- CSR build ----------------

__global__ void k_hist(const int* __restrict__ edst, int* __restrict__ counts) {
    int e = blockIdx.x * 256 + threadIdx.x;
    if (e < N_EDGES) atomicAdd(&counts[edst[e]], 1);
}

// Wave-aggregated exclusive scan: each wave claims a contiguous range via one
// atomic on a global cursor. Ranges are disjoint + correctly sized; absolute
// order across waves is irrelevant for segment-sum correctness.
__global__ void k_scan(const int* __restrict__ counts, int* __restrict__ starts,
                       int* __restrict__ fill, int* __restrict__ cursor) {
    int i = blockIdx.x * 256 + threadIdx.x;
    int lane = threadIdx.x & 63;
    int c = (i < N_NODES) ? counts[i] : 0;
    int incl = c;
    #pragma unroll
    for (int off = 1; off < 64; off <<= 1) {
        int n = __shfl_up(incl, off);
        if (lane >= off) incl += n;
    }
    int total = __shfl(incl, 63);
    int base = 0;
    if (lane == 0) base = atomicAdd(cursor, total);
    base = __shfl(base, 0);
    if (i < N_NODES) {
        int s = base + incl - c;   // exclusive prefix within wave + wave base
        starts[i] = s;
        fill[i] = s;
    }
}

__global__ void k_scatter(const int* __restrict__ esrc, const int* __restrict__ edst,
                          const float* __restrict__ ewt, int* __restrict__ fill,
                          int* __restrict__ es_s, float* __restrict__ ew_s) {
    int e = blockIdx.x * 256 + threadIdx.x;
    if (e < N_EDGES) {
        int d = edst[e];
        int pos = atomicAdd(&fill[d], 1);
        es_s[pos] = esrc[e];
        ew_s[pos] = ewt[e];
    }
}

// ---------------- GEMM1: x[50000x256] @ W1[256x64] -> xW1 ----------------
// 16 rows/block, 256 threads: col = tid&63, row-quad = tid>>6 (4 rows each).
// W1 staged in LDS (exactly 64 KB). x rows read via broadcast float4 loads.
__global__ __launch_bounds__(256) void k_gemm1(const float* __restrict__ x,
                                               const float* __restrict__ W1,
                                               float* __restrict__ xW1) {
    __shared__ float sW1[NFEAT * NHID];   // 65536 B
    int tid = threadIdx.x;
    for (int i = tid * 4; i < NFEAT * NHID; i += 256 * 4) {
        *(float4*)&sW1[i] = *(const float4*)&W1[i];
    }
    __syncthreads();

    int col = tid & 63;
    int rq  = tid >> 6;                    // 0..3
    int row0 = blockIdx.x * 16 + rq * 4;
    const float* x0 = x + (size_t)row0 * NFEAT;

    float acc0 = 0.f, acc1 = 0.f, acc2 = 0.f, acc3 = 0.f;
    for (int k = 0; k < NFEAT; k += 4) {
        float4 a0 = *(const float4*)(x0 + 0 * NFEAT + k);
        float4 a1 = *(const float4*)(x0 + 1 * NFEAT + k);
        float4 a2 = *(const float4*)(x0 + 2 * NFEAT + k);
        float4 a3 = *(const float4*)(x0 + 3 * NFEAT + k);
        float w0 = sW1[(k + 0) * NHID + col];
        float w1 = sW1[(k + 1) * NHID + col];
        float w2 = sW1[(k + 2) * NHID + col];
        float w3 = sW1[(k + 3) * NHID + col];
        acc0 += a0.x * w0 + a0.y * w1 + a0.z * w2 + a0.w * w3;
        acc1 += a1.x * w0 + a1.y * w1 + a1.z * w2 + a1.w * w3;
        acc2 += a2.x * w0 + a2.y * w1 + a2.z * w2 + a2.w * w3;
        acc3 += a3.x * w0 + a3.y * w1 + a3.z * w2 + a3.w * w3;
    }
    float* o = xW1 + (size_t)row0 * NHID + col;
    o[0 * NHID] = acc0;
    o[1 * NHID] = acc1;
    o[2 * NHID] = acc2;
    o[3 * NHID] = acc3;
}

// ---------------- SPMM1 + bias + ReLU ----------------
// One 64-lane group per node, lane = hidden feature. Coalesced 256B gathers.
__global__ void k_spmm1(const float* __restrict__ xW1, const int* __restrict__ starts,
                        const int* __restrict__ counts, const int* __restrict__ es_s,
                        const float* __restrict__ ew_s, const float* __restrict__ b1,
                        float* __restrict__ h) {
    int node = blockIdx.x * 4 + (threadIdx.x >> 6);
    int lane = threadIdx.x & 63;
    int s = starts[node];
    int c = counts[node];
    float acc = 0.f;
    for (int j = 0; j < c; ++j) {
        int src = es_s[s + j];
        float w = ew_s[s + j];
        acc += xW1[(size_t)src * NHID + lane] * w;
    }
    float v = acc + b1[lane];
    h[(size_t)node * NHID + lane] = v > 0.f ? v : 0.f;
}

// ---------------- GEMM2: h[50000x64] @ W2[64x40] -> hW2 ----------------
// 320 threads = 8 rows x 40 cols. W2 staged in LDS.
__global__ __launch_bounds__(320) void k_gemm2(const float* __restrict__ h,
                                               const float* __restrict__ W2,
                                               float* __restrict__ hW2) {
    __shared__ float sW2[NHID * NCLASS];  // 10240 B
    int tid = threadIdx.x;
    for (int i = tid; i < NHID * NCLASS; i += 320) sW2[i] = W2[i];
    __syncthreads();

    int col = tid % NCLASS;
    int r   = tid / NCLASS;               // 0..7
    int row = blockIdx.x * 8 + r;
    const float* hr = h + (size_t)row * NHID;
    float acc = 0.f;
    #pragma unroll
    for (int k = 0; k < NHID; ++k) acc += hr[k] * sW2[k * NCLASS + col];
    hW2[(size_t)row * NCLASS + col] = acc;
}

// ---------------- SPMM2 + bias + log-softmax ----------------
// One 64-lane group per node; lanes 0..39 hold classes. Writes both outputs.
__global__ void k_spmm2(const float* __restrict__ hW2, const int* __restrict__ starts,
                        const int* __restrict__ counts, const int* __restrict__ es_s,
                        const float* __restrict__ ew_s, const float* __restrict__ b2,
                        float* __restrict__ out) {
    int node = blockIdx.x * 4 + (threadIdx.x >> 6);
    int lane = threadIdx.x & 63;
    int lf = lane < NCLASS ? lane : 0;    // clamp so gathers stay in-bounds
    int s = starts[node];
    int c = counts[node];
    float acc = 0.f;
    for (int j = 0; j < c; ++j) {
        int src = es_s[s + j];
        float w = ew_s[s + j];
        acc += hW2[(size_t)src * NCLASS + lf] * w;
    }
    float v = (lane < NCLASS) ? (acc + b2[lf]) : -INFINITY;
    float m = v;
    #pragma unroll
    for (int off = 32; off; off >>= 1) m = fmaxf(m, __shfl_xor(m, off));
    float e = (lane < NCLASS) ? expf(v - m) : 0.f;
    float ssum = e;
    #pragma unroll
    for (int off = 32; off; off >>= 1) ssum += __shfl_xor(ssum, off);
    float ls = logf(ssum);
    if (lane < NCLASS) {
        out[(size_t)node * NCLASS + lane] = v;
        out[(size_t)N_NODES * NCLASS + (size_t)node * NCLASS + lane] = v - m - ls;
    }
}

// ---------------- launch ----------------

extern "C" void kernel_launch(void* const* d_in, const int* in_sizes, int n_in,
                              void* d_out, int out_size, void* d_ws, size_t ws_size,
                              hipStream_t stream) {
    const float* x    = (const float*)d_in[0];
    const float* W1   = (const float*)d_in[1];
    const float* b1   = (const float*)d_in[2];
    const float* W2   = (const float*)d_in[3];
    const float* b2   = (const float*)d_in[4];
    const float* ewt  = (const float*)d_in[5];
    const int*   esrc = (const int*)d_in[6];
    const int*   edst = (const int*)d_in[7];
    float* out = (float*)d_out;

    // workspace layout (all 4-byte elems)
    float* ws   = (float*)d_ws;
    float* xW1  = ws;                          // 3,200,000 f
    float* h    = xW1 + (size_t)N_NODES * NHID;       // 3,200,000 f
    float* hW2  = h + (size_t)N_NODES * NHID;         // 2,000,000 f
    float* ew_s = hW2 + (size_t)N_NODES * NCLASS;     // 800,000 f
    int*   es_s = (int*)(ew_s + N_EDGES);             // 800,000 i
    int*   counts = es_s + N_EDGES;                   // 50,000 i
    int*   cursor = counts + N_NODES;                 // 1 i (adjacent for one memset)
    int*   starts = cursor + 1;                       // 50,000 i
    int*   fill   = starts + N_NODES;                 // 50,000 i

    hipMemsetAsync(counts, 0, (N_NODES + 1) * sizeof(int), stream);

    k_hist<<<N_EDGES / 256, 256, 0, stream>>>(edst, counts);
    k_scan<<<(N_NODES + 255) / 256, 256, 0, stream>>>(counts, starts, fill, cursor);
    k_scatter<<<N_EDGES / 256, 256, 0, stream>>>(esrc, edst, ewt, fill, es_s, ew_s);

    k_gemm1<<<N_NODES / 16, 256, 0, stream>>>(x, W1, xW1);
    k_spmm1<<<N_NODES / 4, 256, 0, stream>>>(xW1, starts, counts, es_s, ew_s, b1, h);
    k_gemm2<<<N_NODES / 8, 320, 0, stream>>>(h, W2, hW2);
    k_spmm2<<<N_NODES / 4, 256, 0, stream>>>(hW2, starts, counts, es_s, ew_s, b2, out);
}

// Round 3
// 304.241 us; speedup vs baseline: 1.6035x; 1.6035x over previous
//
#include <hip/hip_runtime.h>
#include <math.h>

#define N_NODES 50000
#define N_EDGES 800000
#define NFEAT 256
#define NHID 64
#define NCLASS 40
#define NPAD_ROWS 50048   // gemm2 reads h in 64-row blocks: 782*64

typedef __attribute__((ext_vector_type(8))) short bf16x8;
typedef __attribute__((ext_vector_type(4))) float f32x4;

__device__ __forceinline__ ushort f2bf(float f) {
    unsigned u = __float_as_uint(f);
    u += 0x7FFF + ((u >> 16) & 1);          // round-to-nearest-even
    return (ushort)(u >> 16);
}
__device__ __forceinline__ float bf2f(ushort us) {
    return __uint_as_float(((unsigned)us) << 16);
}

// ---------------- CSR build ----------------

__global__ void k_hist(const int* __restrict__ edst, int* __restrict__ counts) {
    int e = blockIdx.x * 256 + threadIdx.x;
    if (e < N_EDGES) atomicAdd(&counts[edst[e]], 1);
}

// Wave-aggregated exclusive scan; ranges disjoint, order irrelevant for segsum.
__global__ void k_scan(const int* __restrict__ counts, int* __restrict__ starts,
                       int* __restrict__ fill, int* __restrict__ cursor) {
    int i = blockIdx.x * 256 + threadIdx.x;
    int lane = threadIdx.x & 63;
    int c = (i < N_NODES) ? counts[i] : 0;
    int incl = c;
    #pragma unroll
    for (int off = 1; off < 64; off <<= 1) {
        int n = __shfl_up(incl, off);
        if (lane >= off) incl += n;
    }
    int total = __shfl(incl, 63);
    int base = 0;
    if (lane == 0) base = atomicAdd(cursor, total);
    base = __shfl(base, 0);
    if (i < N_NODES) {
        int s = base + incl - c;
        starts[i] = s;
        fill[i] = s;
    }
}

__global__ void k_scatter(const int* __restrict__ esrc, const int* __restrict__ edst,
                          const float* __restrict__ ewt, int* __restrict__ fill,
                          int2* __restrict__ es_ew) {
    int e = blockIdx.x * 256 + threadIdx.x;
    if (e < N_EDGES) {
        int d = edst[e];
        int pos = atomicAdd(&fill[d], 1);
        es_ew[pos] = make_int2(esrc[e], __float_as_int(ewt[e]));
    }
}

// ---------------- prep: W1,W2 -> bf16 fragment-ordered tables ----------------
// W1f[(ct*8+ks)*64+lane][j] = bf16(W1[ks*32+(lane>>4)*8+j][ct*16+(lane&15)])
// W2f[(ct*2+ks)*64+lane][j] = bf16(W2pad[ks*32+(lane>>4)*8+j][ct*16+(lane&15)])
__global__ void k_prep(const float* __restrict__ W1, const float* __restrict__ W2,
                       ushort* __restrict__ W1f, ushort* __restrict__ W2f) {
    int idx = blockIdx.x * 256 + threadIdx.x;
    if (idx < 2048) {                        // 4 ct * 8 ks * 64 lanes
        int lane = idx & 63, ctks = idx >> 6;
        int ks = ctks & 7, ct = ctks >> 3;
        int col = ct * 16 + (lane & 15);
        int r0 = ks * 32 + (lane >> 4) * 8;
        bf16x8 frag;
        #pragma unroll
        for (int j = 0; j < 8; ++j) frag[j] = (short)f2bf(W1[(r0 + j) * NHID + col]);
        *(bf16x8*)&W1f[(size_t)idx * 8] = frag;
    } else if (idx < 2048 + 384) {           // 3 ct * 2 ks * 64 lanes
        int i2 = idx - 2048;
        int lane = i2 & 63, ctks = i2 >> 6;
        int ks = ctks & 1, ct = ctks >> 1;
        int col = ct * 16 + (lane & 15);
        int r0 = ks * 32 + (lane >> 4) * 8;
        bf16x8 frag;
        #pragma unroll
        for (int j = 0; j < 8; ++j)
            frag[j] = (short)((col < NCLASS) ? f2bf(W2[(r0 + j) * NCLASS + col]) : 0);
        *(bf16x8*)&W2f[(size_t)i2 * 8] = frag;
    }
}

// ---------------- GEMM1: xW1b = bf16( x @ W1 ) via MFMA ----------------
// 256 thr = 4 waves; block does 16 rows x 64 cols; wave w -> cols w*16..+15.
// x tile staged in LDS as bf16, XOR-swizzled in 16B chunks.
__global__ __launch_bounds__(256) void k_gemm1(const float* __restrict__ x,
                                               const ushort* __restrict__ W1f,
                                               ushort* __restrict__ xW1b) {
    __shared__ ushort sX[16 * 256];          // 8 KB
    int tid = threadIdx.x;
    int w = tid >> 6, lane = tid & 63;
    int row0 = blockIdx.x * 16;

    // B fragments: held in VGPRs for all 8 k-steps
    bf16x8 Bf[8];
    #pragma unroll
    for (int ks = 0; ks < 8; ++ks)
        Bf[ks] = *(const bf16x8*)&W1f[(size_t)((w * 8 + ks) * 64 + lane) * 8];

    // stage x -> LDS bf16: thread t handles row=t&15, cols (t>>4)*16..+15
    {
        int row = tid & 15;
        int colbase = (tid >> 4) * 16;
        const float* xp = x + (size_t)(row0 + row) * NFEAT + colbase;
        #pragma unroll
        for (int c2 = 0; c2 < 2; ++c2) {
            float4 v0 = *(const float4*)(xp + c2 * 8);
            float4 v1 = *(const float4*)(xp + c2 * 8 + 4);
            bf16x8 fr;
            fr[0] = (short)f2bf(v0.x); fr[1] = (short)f2bf(v0.y);
            fr[2] = (short)f2bf(v0.z); fr[3] = (short)f2bf(v0.w);
            fr[4] = (short)f2bf(v1.x); fr[5] = (short)f2bf(v1.y);
            fr[6] = (short)f2bf(v1.z); fr[7] = (short)f2bf(v1.w);
            int chunk = colbase / 8 + c2;                 // 0..31
            *(bf16x8*)&sX[row * 256 + ((chunk ^ (row & 7)) * 8)] = fr;
        }
    }
    __syncthreads();

    f32x4 acc = {0.f, 0.f, 0.f, 0.f};
    int arow = lane & 15;
    #pragma unroll
    for (int ks = 0; ks < 8; ++ks) {
        int chunk = ks * 4 + (lane >> 4);
        bf16x8 Af = *(const bf16x8*)&sX[arow * 256 + ((chunk ^ (arow & 7)) * 8)];
        acc = __builtin_amdgcn_mfma_f32_16x16x32_bf16(Af, Bf[ks], acc, 0, 0, 0);
    }
    int col = w * 16 + (lane & 15);
    int rbase = row0 + (lane >> 4) * 4;
    #pragma unroll
    for (int r = 0; r < 4; ++r)
        xW1b[(size_t)(rbase + r) * NHID + col] = f2bf(acc[r]);
}

// ---------------- SPMM1 + bias + ReLU -> h (bf16) ----------------
__global__ void k_spmm1(const ushort* __restrict__ xW1b, const int* __restrict__ starts,
                        const int* __restrict__ counts, const int2* __restrict__ es_ew,
                        const float* __restrict__ b1, ushort* __restrict__ h_b) {
    int node = blockIdx.x * 4 + (threadIdx.x >> 6);
    int lane = threadIdx.x & 63;
    int s = starts[node];
    int c = counts[node];
    float acc0 = 0.f, acc1 = 0.f;
    int j = 0;
    for (; j + 1 < c; j += 2) {
        int2 e0 = es_ew[s + j];
        int2 e1 = es_ew[s + j + 1];
        acc0 += __int_as_float(e0.y) * bf2f(xW1b[(size_t)e0.x * NHID + lane]);
        acc1 += __int_as_float(e1.y) * bf2f(xW1b[(size_t)e1.x * NHID + lane]);
    }
    if (j < c) {
        int2 e0 = es_ew[s + j];
        acc0 += __int_as_float(e0.y) * bf2f(xW1b[(size_t)e0.x * NHID + lane]);
    }
    float v = acc0 + acc1 + b1[lane];
    h_b[(size_t)node * NHID + lane] = f2bf(v > 0.f ? v : 0.f);
}

// ---------------- GEMM2: hW2b = bf16( h @ W2 ) via MFMA ----------------
// 256 thr = 4 waves; wave w -> rows blockIdx*64 + w*16, all 3 col-tiles (48 pad).
__global__ __launch_bounds__(256) void k_gemm2(const ushort* __restrict__ h_b,
                                               const ushort* __restrict__ W2f,
                                               ushort* __restrict__ hW2b) {
    int tid = threadIdx.x;
    int w = tid >> 6, lane = tid & 63;
    int row0 = blockIdx.x * 64 + w * 16;

    f32x4 acc[3] = {{0.f,0.f,0.f,0.f},{0.f,0.f,0.f,0.f},{0.f,0.f,0.f,0.f}};
    #pragma unroll
    for (int ks = 0; ks < 2; ++ks) {
        bf16x8 Af = *(const bf16x8*)&h_b[(size_t)(row0 + (lane & 15)) * NHID
                                         + ks * 32 + (lane >> 4) * 8];
        #pragma unroll
        for (int ct = 0; ct < 3; ++ct) {
            bf16x8 Bf = *(const bf16x8*)&W2f[(size_t)((ct * 2 + ks) * 64 + lane) * 8];
            acc[ct] = __builtin_amdgcn_mfma_f32_16x16x32_bf16(Af, Bf, acc[ct], 0, 0, 0);
        }
    }
    int rbase = row0 + (lane >> 4) * 4;
    #pragma unroll
    for (int ct = 0; ct < 3; ++ct) {
        int col = ct * 16 + (lane & 15);
        if (col < NCLASS) {
            #pragma unroll
            for (int r = 0; r < 4; ++r) {
                int row = rbase + r;
                if (row < N_NODES)
                    hW2b[(size_t)row * NCLASS + col] = f2bf(acc[ct][r]);
            }
        }
    }
}

// ---------------- SPMM2 + bias + log-softmax -> out (f32 x2) ----------------
__global__ void k_spmm2(const ushort* __restrict__ hW2b, const int* __restrict__ starts,
                        const int* __restrict__ counts, const int2* __restrict__ es_ew,
                        const float* __restrict__ b2, float* __restrict__ out) {
    int node = blockIdx.x * 4 + (threadIdx.x >> 6);
    int lane = threadIdx.x & 63;
    int lf = lane < NCLASS ? lane : 0;
    int s = starts[node];
    int c = counts[node];
    float acc0 = 0.f, acc1 = 0.f;
    int j = 0;
    for (; j + 1 < c; j += 2) {
        int2 e0 = es_ew[s + j];
        int2 e1 = es_ew[s + j + 1];
        acc0 += __int_as_float(e0.y) * bf2f(hW2b[(size_t)e0.x * NCLASS + lf]);
        acc1 += __int_as_float(e1.y) * bf2f(hW2b[(size_t)e1.x * NCLASS + lf]);
    }
    if (j < c) {
        int2 e0 = es_ew[s + j];
        acc0 += __int_as_float(e0.y) * bf2f(hW2b[(size_t)e0.x * NCLASS + lf]);
    }
    float v = (lane < NCLASS) ? (acc0 + acc1 + b2[lf]) : -INFINITY;
    float m = v;
    #pragma unroll
    for (int off = 32; off; off >>= 1) m = fmaxf(m, __shfl_xor(m, off));
    float e = (lane < NCLASS) ? __expf(v - m) : 0.f;
    float ssum = e;
    #pragma unroll
    for (int off = 32; off; off >>= 1) ssum += __shfl_xor(ssum, off);
    float ls = __logf(ssum);
    if (lane < NCLASS) {
        out[(size_t)node * NCLASS + lane] = v;
        out[(size_t)N_NODES * NCLASS + (size_t)node * NCLASS + lane] = v - m - ls;
    }
}

// ---------------- launch ----------------

extern "C" void kernel_launch(void* const* d_in, const int* in_sizes, int n_in,
                              void* d_out, int out_size, void* d_ws, size_t ws_size,
                              hipStream_t stream) {
    const float* x    = (const float*)d_in[0];
    const float* W1   = (const float*)d_in[1];
    const float* b1   = (const float*)d_in[2];
    const float* W2   = (const float*)d_in[3];
    const float* b2   = (const float*)d_in[4];
    const float* ewt  = (const float*)d_in[5];
    const int*   esrc = (const int*)d_in[6];
    const int*   edst = (const int*)d_in[7];
    float* out = (float*)d_out;

    // workspace layout
    char* p = (char*)d_ws;
    ushort* xW1b = (ushort*)p;                 p += (size_t)N_NODES * NHID * 2;      // 6.4 MB
    ushort* h_b  = (ushort*)p;                 p += (size_t)NPAD_ROWS * NHID * 2;    // 6.4 MB
    ushort* hW2b = (ushort*)p;                 p += (size_t)N_NODES * NCLASS * 2;    // 4.0 MB
    int2*   es_ew = (int2*)p;                  p += (size_t)N_EDGES * 8;             // 6.4 MB
    ushort* W1f  = (ushort*)p;                 p += 2048 * 8 * 2;                    // 32 KB
    ushort* W2f  = (ushort*)p;                 p += 384 * 8 * 2;                     // 6 KB
    int* counts  = (int*)p;                    p += N_NODES * 4;
    int* cursor  = (int*)p;                    p += 4;
    int* starts  = (int*)p;                    p += N_NODES * 4;
    int* fill    = (int*)p;                    p += N_NODES * 4;

    hipMemsetAsync(counts, 0, (N_NODES + 1) * sizeof(int), stream);

    k_hist<<<N_EDGES / 256, 256, 0, stream>>>(edst, counts);
    k_scan<<<(N_NODES + 255) / 256, 256, 0, stream>>>(counts, starts, fill, cursor);
    k_scatter<<<N_EDGES / 256, 256, 0, stream>>>(esrc, edst, ewt, fill, es_ew);
    k_prep<<<10, 256, 0, stream>>>(W1, W2, W1f, W2f);

    k_gemm1<<<N_NODES / 16, 256, 0, stream>>>(x, W1f, xW1b);
    k_spmm1<<<N_NODES / 4, 256, 0, stream>>>(xW1b, starts, counts, es_ew, b1, h_b);
    k_gemm2<<<(NPAD_ROWS) / 64, 256, 0, stream>>>(h_b, W2f, hW2b);
    k_spmm2<<<N_NODES / 4, 256, 0, stream>>>(hW2b, starts, counts, es_ew, b2, out);
}

// Round 4
// 242.026 us; speedup vs baseline: 2.0157x; 1.2571x over previous
//
#include <hip/hip_runtime.h>
#include <math.h>

#define N_NODES 50000
#define N_EDGES 800000
#define NFEAT 256
#define NHID 64
#define NCLASS 40
#define NPAD_ROWS 50048   // gemm2 reads h in 64-row blocks: 782*64
#define NPB 16            // nodes per bucket
#define NB  3125          // 50000 / 16
#define BIN_EPB 8192      // edges per binning/hist block

typedef __attribute__((ext_vector_type(8))) short bf16x8;
typedef __attribute__((ext_vector_type(4))) float f32x4;

__device__ __forceinline__ ushort f2bf(float f) {
    unsigned u = __float_as_uint(f);
    u += 0x7FFF + ((u >> 16) & 1);          // round-to-nearest-even
    return (ushort)(u >> 16);
}
__device__ __forceinline__ float bf2f(ushort us) {
    return __uint_as_float(((unsigned)us) << 16);
}

// ---------------- bucket CSR build ----------------

__global__ __launch_bounds__(256) void k_bhist(const int* __restrict__ edst,
                                               int* __restrict__ bcnt) {
    __shared__ int lh[NB];
    int tid = threadIdx.x;
    for (int i = tid; i < NB; i += 256) lh[i] = 0;
    __syncthreads();
    int base = blockIdx.x * BIN_EPB;
    for (int k = 0; k < BIN_EPB; k += 256) {
        int e = base + k + tid;
        if (e < N_EDGES) atomicAdd(&lh[edst[e] >> 4], 1);
    }
    __syncthreads();
    for (int i = tid; i < NB; i += 256) {
        int c = lh[i];
        if (c) atomicAdd(&bcnt[i], c);
    }
}

// Wave-aggregated allocation of disjoint per-bucket ranges (order irrelevant).
__global__ void k_bscan(const int* __restrict__ bcnt, int* __restrict__ bstart,
                        int* __restrict__ bcur, int* __restrict__ cursor) {
    int i = blockIdx.x * 256 + threadIdx.x;
    int lane = threadIdx.x & 63;
    int c = (i < NB) ? bcnt[i] : 0;
    int incl = c;
    #pragma unroll
    for (int off = 1; off < 64; off <<= 1) {
        int n = __shfl_up(incl, off);
        if (lane >= off) incl += n;
    }
    int total = __shfl(incl, 63);
    int base = 0;
    if (lane == 0) base = atomicAdd(cursor, total);
    base = __shfl(base, 0);
    if (i < NB) {
        int s = base + incl - c;
        bstart[i] = s;
        bcur[i] = s;
    }
}

// Two-phase block-local binning: LDS count -> claim contiguous ranges ->
// scatter packed payloads {src | dstl<<16, wt} into claimed slots.
__global__ __launch_bounds__(256) void k_bin(const int* __restrict__ esrc,
                                             const int* __restrict__ edst,
                                             const float* __restrict__ ewt,
                                             int* __restrict__ bcur,
                                             int2* __restrict__ binned) {
    __shared__ int lcnt[NB];
    __shared__ int lbase[NB];
    int tid = threadIdx.x;
    for (int i = tid; i < NB; i += 256) lcnt[i] = 0;
    __syncthreads();
    int base = blockIdx.x * BIN_EPB;
    for (int k = 0; k < BIN_EPB; k += 256) {
        int e = base + k + tid;
        if (e < N_EDGES) atomicAdd(&lcnt[edst[e] >> 4], 1);
    }
    __syncthreads();
    for (int i = tid; i < NB; i += 256) {
        int c = lcnt[i];
        lbase[i] = c ? atomicAdd(&bcur[i], c) : 0;
        lcnt[i] = 0;
    }
    __syncthreads();
    for (int k = 0; k < BIN_EPB; k += 256) {
        int e = base + k + tid;
        if (e < N_EDGES) {
            int d = edst[e];
            int b = d >> 4;
            int pos = lbase[b] + atomicAdd(&lcnt[b], 1);
            binned[pos] = make_int2(esrc[e] | ((d & 15) << 16), __float_as_int(ewt[e]));
        }
    }
}

// ---------------- prep: W1,W2 -> bf16 fragment-ordered tables ----------------

__global__ void k_prep(const float* __restrict__ W1, const float* __restrict__ W2,
                       ushort* __restrict__ W1f, ushort* __restrict__ W2f) {
    int idx = blockIdx.x * 256 + threadIdx.x;
    if (idx < 2048) {                        // 4 ct * 8 ks * 64 lanes
        int lane = idx & 63, ctks = idx >> 6;
        int ks = ctks & 7, ct = ctks >> 3;
        int col = ct * 16 + (lane & 15);
        int r0 = ks * 32 + (lane >> 4) * 8;
        bf16x8 frag;
        #pragma unroll
        for (int j = 0; j < 8; ++j) frag[j] = (short)f2bf(W1[(r0 + j) * NHID + col]);
        *(bf16x8*)&W1f[(size_t)idx * 8] = frag;
    } else if (idx < 2048 + 384) {           // 3 ct * 2 ks * 64 lanes
        int i2 = idx - 2048;
        int lane = i2 & 63, ctks = i2 >> 6;
        int ks = ctks & 1, ct = ctks >> 1;
        int col = ct * 16 + (lane & 15);
        int r0 = ks * 32 + (lane >> 4) * 8;
        bf16x8 frag;
        #pragma unroll
        for (int j = 0; j < 8; ++j)
            frag[j] = (short)((col < NCLASS) ? f2bf(W2[(r0 + j) * NCLASS + col]) : 0);
        *(bf16x8*)&W2f[(size_t)i2 * 8] = frag;
    }
}

// ---------------- GEMM1: xW1b = bf16( x @ W1 ) via MFMA ----------------

__global__ __launch_bounds__(256) void k_gemm1(const float* __restrict__ x,
                                               const ushort* __restrict__ W1f,
                                               ushort* __restrict__ xW1b) {
    __shared__ ushort sX[16 * 256];          // 8 KB
    int tid = threadIdx.x;
    int w = tid >> 6, lane = tid & 63;
    int row0 = blockIdx.x * 16;

    bf16x8 Bf[8];
    #pragma unroll
    for (int ks = 0; ks < 8; ++ks)
        Bf[ks] = *(const bf16x8*)&W1f[(size_t)((w * 8 + ks) * 64 + lane) * 8];

    {
        int row = tid & 15;
        int colbase = (tid >> 4) * 16;
        const float* xp = x + (size_t)(row0 + row) * NFEAT + colbase;
        #pragma unroll
        for (int c2 = 0; c2 < 2; ++c2) {
            float4 v0 = *(const float4*)(xp + c2 * 8);
            float4 v1 = *(const float4*)(xp + c2 * 8 + 4);
            bf16x8 fr;
            fr[0] = (short)f2bf(v0.x); fr[1] = (short)f2bf(v0.y);
            fr[2] = (short)f2bf(v0.z); fr[3] = (short)f2bf(v0.w);
            fr[4] = (short)f2bf(v1.x); fr[5] = (short)f2bf(v1.y);
            fr[6] = (short)f2bf(v1.z); fr[7] = (short)f2bf(v1.w);
            int chunk = colbase / 8 + c2;                 // 0..31
            *(bf16x8*)&sX[row * 256 + ((chunk ^ (row & 7)) * 8)] = fr;
        }
    }
    __syncthreads();

    f32x4 acc = {0.f, 0.f, 0.f, 0.f};
    int arow = lane & 15;
    #pragma unroll
    for (int ks = 0; ks < 8; ++ks) {
        int chunk = ks * 4 + (lane >> 4);
        bf16x8 Af = *(const bf16x8*)&sX[arow * 256 + ((chunk ^ (arow & 7)) * 8)];
        acc = __builtin_amdgcn_mfma_f32_16x16x32_bf16(Af, Bf[ks], acc, 0, 0, 0);
    }
    int col = w * 16 + (lane & 15);
    int rbase = row0 + (lane >> 4) * 4;
    #pragma unroll
    for (int r = 0; r < 4; ++r)
        xW1b[(size_t)(rbase + r) * NHID + col] = f2bf(acc[r]);
}

// ---------------- SPMM1 (bucketed) + bias + ReLU -> h (bf16) ----------------
// One wave per 16-node bucket. acc column `lane` is thread-private -> no sync.
__global__ __launch_bounds__(64) void k_spmm1b(const ushort* __restrict__ xW1b,
                                               const int* __restrict__ bstart,
                                               const int* __restrict__ bcur,
                                               const int2* __restrict__ binned,
                                               const float* __restrict__ b1,
                                               ushort* __restrict__ h_b) {
    __shared__ float acc[NPB * NHID];        // 4 KB
    int lane = threadIdx.x;
    int b = blockIdx.x;
    #pragma unroll
    for (int n = 0; n < NPB; ++n) acc[n * NHID + lane] = 0.f;

    int s = bstart[b], e = bcur[b];
    int j = s;
    for (; j + 8 <= e; j += 8) {
        int2 p[8];
        #pragma unroll
        for (int k = 0; k < 8; ++k) p[k] = binned[j + k];
        float g[8];
        #pragma unroll
        for (int k = 0; k < 8; ++k)
            g[k] = bf2f(xW1b[(p[k].x & 0xFFFF) * NHID + lane]);
        #pragma unroll
        for (int k = 0; k < 8; ++k)
            acc[(p[k].x >> 16) * NHID + lane] += __int_as_float(p[k].y) * g[k];
    }
    for (; j < e; ++j) {
        int2 p0 = binned[j];
        float g0 = bf2f(xW1b[(p0.x & 0xFFFF) * NHID + lane]);
        acc[(p0.x >> 16) * NHID + lane] += __int_as_float(p0.y) * g0;
    }

    float bias = b1[lane];
    #pragma unroll
    for (int n = 0; n < NPB; ++n) {
        float v = acc[n * NHID + lane] + bias;
        h_b[(size_t)(b * NPB + n) * NHID + lane] = f2bf(v > 0.f ? v : 0.f);
    }
}

// ---------------- GEMM2: hW2b = bf16( h @ W2 ) via MFMA ----------------

__global__ __launch_bounds__(256) void k_gemm2(const ushort* __restrict__ h_b,
                                               const ushort* __restrict__ W2f,
                                               ushort* __restrict__ hW2b) {
    int tid = threadIdx.x;
    int w = tid >> 6, lane = tid & 63;
    int row0 = blockIdx.x * 64 + w * 16;

    f32x4 acc[3] = {{0.f,0.f,0.f,0.f},{0.f,0.f,0.f,0.f},{0.f,0.f,0.f,0.f}};
    #pragma unroll
    for (int ks = 0; ks < 2; ++ks) {
        bf16x8 Af = *(const bf16x8*)&h_b[(size_t)(row0 + (lane & 15)) * NHID
                                         + ks * 32 + (lane >> 4) * 8];
        #pragma unroll
        for (int ct = 0; ct < 3; ++ct) {
            bf16x8 Bf = *(const bf16x8*)&W2f[(size_t)((ct * 2 + ks) * 64 + lane) * 8];
            acc[ct] = __builtin_amdgcn_mfma_f32_16x16x32_bf16(Af, Bf, acc[ct], 0, 0, 0);
        }
    }
    int rbase = row0 + (lane >> 4) * 4;
    #pragma unroll
    for (int ct = 0; ct < 3; ++ct) {
        int col = ct * 16 + (lane & 15);
        if (col < NCLASS) {
            #pragma unroll
            for (int r = 0; r < 4; ++r) {
                int row = rbase + r;
                if (row < N_NODES)
                    hW2b[(size_t)row * NCLASS + col] = f2bf(acc[ct][r]);
            }
        }
    }
}

// ---------------- SPMM2 (bucketed) + bias + log-softmax -> out ----------------
// acc stride 64 so lanes 40..63 harmlessly accumulate into unused columns.
__global__ __launch_bounds__(64) void k_spmm2b(const ushort* __restrict__ hW2b,
                                               const int* __restrict__ bstart,
                                               const int* __restrict__ bcur,
                                               const int2* __restrict__ binned,
                                               const float* __restrict__ b2,
                                               float* __restrict__ out) {
    __shared__ float acc[NPB * 64];          // 4 KB
    int lane = threadIdx.x;
    int b = blockIdx.x;
    int lf = lane < NCLASS ? lane : 0;
    #pragma unroll
    for (int n = 0; n < NPB; ++n) acc[n * 64 + lane] = 0.f;

    int s = bstart[b], e = bcur[b];
    int j = s;
    for (; j + 8 <= e; j += 8) {
        int2 p[8];
        #pragma unroll
        for (int k = 0; k < 8; ++k) p[k] = binned[j + k];
        float g[8];
        #pragma unroll
        for (int k = 0; k < 8; ++k)
            g[k] = bf2f(hW2b[(p[k].x & 0xFFFF) * NCLASS + lf]);
        #pragma unroll
        for (int k = 0; k < 8; ++k)
            acc[(p[k].x >> 16) * 64 + lane] += __int_as_float(p[k].y) * g[k];
    }
    for (; j < e; ++j) {
        int2 p0 = binned[j];
        float g0 = bf2f(hW2b[(p0.x & 0xFFFF) * NCLASS + lf]);
        acc[(p0.x >> 16) * 64 + lane] += __int_as_float(p0.y) * g0;
    }

    float bias = (lane < NCLASS) ? b2[lane] : 0.f;
    for (int n = 0; n < NPB; ++n) {
        float v = (lane < NCLASS) ? (acc[n * 64 + lane] + bias) : -INFINITY;
        float m = v;
        #pragma unroll
        for (int off = 32; off; off >>= 1) m = fmaxf(m, __shfl_xor(m, off));
        float ex = (lane < NCLASS) ? __expf(v - m) : 0.f;
        float ssum = ex;
        #pragma unroll
        for (int off = 32; off; off >>= 1) ssum += __shfl_xor(ssum, off);
        float ls = __logf(ssum);
        if (lane < NCLASS) {
            int node = b * NPB + n;
            out[(size_t)node * NCLASS + lane] = v;
            out[(size_t)N_NODES * NCLASS + (size_t)node * NCLASS + lane] = v - m - ls;
        }
    }
}

// ---------------- launch ----------------

extern "C" void kernel_launch(void* const* d_in, const int* in_sizes, int n_in,
                              void* d_out, int out_size, void* d_ws, size_t ws_size,
                              hipStream_t stream) {
    const float* x    = (const float*)d_in[0];
    const float* W1   = (const float*)d_in[1];
    const float* b1   = (const float*)d_in[2];
    const float* W2   = (const float*)d_in[3];
    const float* b2   = (const float*)d_in[4];
    const float* ewt  = (const float*)d_in[5];
    const int*   esrc = (const int*)d_in[6];
    const int*   edst = (const int*)d_in[7];
    float* out = (float*)d_out;

    // workspace layout (16B-aligned chunks)
    char* p = (char*)d_ws;
    ushort* xW1b = (ushort*)p;   p += (size_t)N_NODES * NHID * 2;      // 6.40 MB
    ushort* h_b  = (ushort*)p;   p += (size_t)NPAD_ROWS * NHID * 2;    // 6.41 MB
    ushort* hW2b = (ushort*)p;   p += (size_t)N_NODES * NCLASS * 2;    // 4.00 MB
    int2*   binned = (int2*)p;   p += (size_t)N_EDGES * 8;             // 6.40 MB
    ushort* W1f  = (ushort*)p;   p += 2048 * 8 * 2;                    // 32 KB
    ushort* W2f  = (ushort*)p;   p += 384 * 8 * 2;                     // 6 KB
    int* bcnt    = (int*)p;      p += NB * 4;
    int* cursor  = (int*)p;      p += 4;
    int* bstart  = (int*)p;      p += NB * 4;
    int* bcur    = (int*)p;      p += NB * 4;

    hipMemsetAsync(bcnt, 0, (NB + 1) * sizeof(int), stream);  // bcnt + cursor

    int nBinBlocks = (N_EDGES + BIN_EPB - 1) / BIN_EPB;       // 98
    k_bhist<<<nBinBlocks, 256, 0, stream>>>(edst, bcnt);
    k_bscan<<<(NB + 255) / 256, 256, 0, stream>>>(bcnt, bstart, bcur, cursor);
    k_bin<<<nBinBlocks, 256, 0, stream>>>(esrc, edst, ewt, bcur, binned);
    k_prep<<<10, 256, 0, stream>>>(W1, W2, W1f, W2f);

    k_gemm1<<<N_NODES / 16, 256, 0, stream>>>(x, W1f, xW1b);
    k_spmm1b<<<NB, 64, 0, stream>>>(xW1b, bstart, bcur, binned, b1, h_b);
    k_gemm2<<<NPAD_ROWS / 64, 256, 0, stream>>>(h_b, W2f, hW2b);
    k_spmm2b<<<NB, 64, 0, stream>>>(hW2b, bstart, bcur, binned, b2, out);
}